// Round 1
// baseline (413.941 us; speedup 1.0000x reference)
//
#include <hip/hip_runtime.h>
#include <math.h>

// Problem constants (reference: N=8192, D=256, threshold 0.85, eps 1e-12)
#define NROWS 8192
#define DIM   256
#define TILE  64
#define BK    64
#define NT    (NROWS / TILE)      // 128 tile-blocks per side
#define SIM_THR 0.85f

// d_ws layout:
//   [0:16)                      header: f[0]=max, f[1]=sum, u[2]=count, u[3]=edge_count
//   [16 : 16+8MB)               normed embeddings (fp32, 8192x256)
//   [16+8MB : ...]              edge list (int2)
#define NORM_OFF  16
#define EDGE_OFF  (16 + NROWS * DIM * 4)

__device__ inline void atomicMaxF(float* addr, float val) {
    // Standard sign-split trick; works with init = -inf (0xFF800000).
    if (val >= 0.f) atomicMax((int*)addr, __float_as_int(val));
    else            atomicMin((unsigned int*)addr, __float_as_uint(val));
}

__global__ void init_kernel(float* wsf) {
    if (threadIdx.x == 0) {
        wsf[0] = -INFINITY;                 // running max
        wsf[1] = 0.f;                       // running sum
        ((unsigned int*)wsf)[2] = 0u;       // count > thr
        ((unsigned int*)wsf)[3] = 0u;       // edge count
    }
}

// One wave per row: 64 lanes x float4 = 256 elements.
__global__ __launch_bounds__(256) void normalize_kernel(const float* __restrict__ x,
                                                        float* __restrict__ y) {
    int row  = blockIdx.x * 4 + (threadIdx.x >> 6);
    int lane = threadIdx.x & 63;
    float4 v = ((const float4*)(x + (size_t)row * DIM))[lane];
    float ss = v.x * v.x + v.y * v.y + v.z * v.z + v.w * v.w;
    #pragma unroll
    for (int off = 32; off; off >>= 1) ss += __shfl_xor(ss, off);
    float norm = fmaxf(sqrtf(ss), 1e-12f);   // matches F.normalize eps clamp
    float4 o;
    o.x = v.x / norm; o.y = v.y / norm; o.z = v.z / norm; o.w = v.w / norm;
    ((float4*)(y + (size_t)row * DIM))[lane] = o;
}

// 64x64 output tile per block, 256 threads, 4x4 per thread, fp32 VALU FMA.
// Upper-triangular tiles only (bj >= bi); off-diag tiles weighted x2.
__global__ __launch_bounds__(256) void sim_kernel(const float* __restrict__ nrm,
                                                  float* wsf, int2* edges, int cap) {
    int bi = blockIdx.y, bj = blockIdx.x;
    if (bj < bi) return;

    // k-major tiles, pad 68 floats (272B, 16B-aligned rows; bank stride 4)
    __shared__ __align__(16) float As[BK][68];
    __shared__ __align__(16) float Bs[BK][68];
    __shared__ float sred[12];   // block reduction scratch (4 waves x 3)

    int t  = threadIdx.x;
    int tx = t & 15;             // 0..15 -> output col group
    int ty = t >> 4;             // 0..15 -> output row group
    int i0 = bi * TILE, j0 = bj * TILE;

    float acc[4][4] = {};

    for (int kc = 0; kc < DIM; kc += BK) {
        // ---- stage: each thread loads 4 float4 of A and B, transposes into k-major LDS
        int kv = t & 15;         // which float4 along k
        int r0 = t >> 4;         // 0..15
        #pragma unroll
        for (int q = 0; q < 4; ++q) {
            int r = r0 + q * 16;
            float4 a = *(const float4*)(nrm + (size_t)(i0 + r) * DIM + kc + kv * 4);
            float4 b = *(const float4*)(nrm + (size_t)(j0 + r) * DIM + kc + kv * 4);
            As[kv * 4 + 0][r] = a.x; As[kv * 4 + 1][r] = a.y;
            As[kv * 4 + 2][r] = a.z; As[kv * 4 + 3][r] = a.w;
            Bs[kv * 4 + 0][r] = b.x; Bs[kv * 4 + 1][r] = b.y;
            Bs[kv * 4 + 2][r] = b.z; Bs[kv * 4 + 3][r] = b.w;
        }
        __syncthreads();

        // ---- compute: per k, b128 fragment reads (A: 4-addr broadcast, B: 2-way free)
        #pragma unroll
        for (int k = 0; k < BK; ++k) {
            float4 a = *(const float4*)&As[k][ty * 4];
            float4 b = *(const float4*)&Bs[k][tx * 4];
            float av[4] = {a.x, a.y, a.z, a.w};
            float bv[4] = {b.x, b.y, b.z, b.w};
            #pragma unroll
            for (int m = 0; m < 4; ++m)
                #pragma unroll
                for (int n = 0; n < 4; ++n)
                    acc[m][n] = fmaf(av[m], bv[n], acc[m][n]);
        }
        __syncthreads();
    }

    // ---- epilogue: fused reductions + sparse edge emission
    bool diag = (bi == bj);
    float        w  = diag ? 1.f : 2.f;
    unsigned int wi = diag ? 1u  : 2u;

    float lmax = -INFINITY, lsum = 0.f;
    unsigned int lcnt = 0;
    #pragma unroll
    for (int m = 0; m < 4; ++m) {
        #pragma unroll
        for (int n = 0; n < 4; ++n) {
            int gi = i0 + ty * 4 + m, gj = j0 + tx * 4 + n;
            float s = acc[m][n];
            if (gi != gj) {
                lmax = fmaxf(lmax, s);
                lsum += s;
                if (s > SIM_THR) {
                    lcnt++;
                    unsigned int idx = atomicAdd(&((unsigned int*)wsf)[3], 1u);
                    if (idx < (unsigned int)cap) edges[idx] = make_int2(gi, gj);
                }
            }
        }
    }
    // wave reduce
    #pragma unroll
    for (int off = 32; off; off >>= 1) {
        lmax = fmaxf(lmax, __shfl_xor(lmax, off));
        lsum += __shfl_xor(lsum, off);
        lcnt += __shfl_xor(lcnt, off);
    }
    int wid = t >> 6, lane = t & 63;
    if (lane == 0) { sred[wid] = lmax; sred[4 + wid] = lsum; ((unsigned int*)sred)[8 + wid] = lcnt; }
    __syncthreads();
    if (t == 0) {
        float bm = fmaxf(fmaxf(sred[0], sred[1]), fmaxf(sred[2], sred[3]));
        float bs = sred[4] + sred[5] + sred[6] + sred[7];
        unsigned int bc = ((unsigned int*)sred)[8] + ((unsigned int*)sred)[9]
                        + ((unsigned int*)sred)[10] + ((unsigned int*)sred)[11];
        atomicMaxF(&wsf[0], bm);
        atomicAdd(&wsf[1], bs * w);
        if (bc) atomicAdd(&((unsigned int*)wsf)[2], bc * wi);
    }
}

// Single block: reference's exact 16-iteration min-label + pointer-jump on LDS,
// then root count, feature assembly, and the 4->16->1 MLP.
__global__ __launch_bounds__(1024) void finalize_kernel(const float* wsf, const int2* edges, int cap,
                                                        const float* __restrict__ w1,
                                                        const float* __restrict__ b1,
                                                        const float* __restrict__ w2,
                                                        const float* __restrict__ b2,
                                                        float* __restrict__ out) {
    __shared__ int lab[NROWS];
    __shared__ int tmp[NROWS];
    __shared__ int wsum[16];
    int t = threadIdx.x;
    for (int i = t; i < NROWS; i += 1024) lab[i] = i;
    unsigned int ec = ((const unsigned int*)wsf)[3];
    if (ec > (unsigned int)cap) ec = (unsigned int)cap;
    __syncthreads();

    // iters = ceil(log2(8192)) + 3 = 16, matching the reference exactly.
    for (int it = 0; it < 16; ++it) {
        for (int i = t; i < NROWS; i += 1024) tmp[i] = lab[i];   // self (adj incl. eye)
        __syncthreads();
        for (unsigned int e = t; e < ec; e += 1024) {
            int u = edges[e].x, v = edges[e].y;
            atomicMin(&tmp[u], lab[v]);
            atomicMin(&tmp[v], lab[u]);
        }
        __syncthreads();
        for (int i = t; i < NROWS; i += 1024) lab[i] = tmp[tmp[i]];  // pointer jump
        __syncthreads();
    }

    int lc = 0;
    for (int i = t; i < NROWS; i += 1024) lc += (lab[i] == i);
    #pragma unroll
    for (int off = 32; off; off >>= 1) lc += __shfl_xor(lc, off);
    if ((t & 63) == 0) wsum[t >> 6] = lc;
    __syncthreads();

    if (t == 0) {
        int roots = 0;
        #pragma unroll
        for (int q = 0; q < 16; ++q) roots += wsum[q];
        const float n_pairs = 67100672.0f;                 // 8192*8191
        float feats[4];
        feats[0] = wsf[0];
        feats[1] = wsf[1] / n_pairs;
        feats[2] = (float)((const unsigned int*)wsf)[2] / n_pairs;
        feats[3] = (float)roots / (float)NROWS;
        float acc2 = b2[0];
        for (int j = 0; j < 16; ++j) {
            float hj = b1[j];
            #pragma unroll
            for (int i = 0; i < 4; ++i) hj = fmaf(feats[i], w1[i * 16 + j], hj);
            float g = 0.5f * hj * (1.0f + erff(hj * 0.70710678118f));  // exact gelu
            acc2 = fmaf(g, w2[j], acc2);
        }
        out[0] = 1.0f / (1.0f + expf(-acc2));
    }
}

extern "C" void kernel_launch(void* const* d_in, const int* in_sizes, int n_in,
                              void* d_out, int out_size, void* d_ws, size_t ws_size,
                              hipStream_t stream) {
    const float* cls = (const float*)d_in[0];
    const float* w1  = (const float*)d_in[1];
    const float* b1  = (const float*)d_in[2];
    const float* w2  = (const float*)d_in[3];
    const float* b2  = (const float*)d_in[4];
    float* out = (float*)d_out;

    float* wsf    = (float*)d_ws;
    float* normed = (float*)((char*)d_ws + NORM_OFF);
    int2*  edges  = (int2*)((char*)d_ws + EDGE_OFF);
    long long avail = (long long)ws_size - (long long)EDGE_OFF;
    int cap = (int)(avail > 0 ? (avail / 8 > 4194304 ? 4194304 : avail / 8) : 0);

    init_kernel<<<1, 64, 0, stream>>>(wsf);
    normalize_kernel<<<NROWS / 4, 256, 0, stream>>>(cls, normed);
    sim_kernel<<<dim3(NT, NT), 256, 0, stream>>>(normed, wsf, edges, cap);
    finalize_kernel<<<1, 1024, 0, stream>>>(wsf, edges, cap, w1, b1, w2, b2, out);
}

// Round 2
// 151.179 us; speedup vs baseline: 2.7381x; 2.7381x over previous
//
#include <hip/hip_runtime.h>
#include <math.h>

// N=8192, D=256. sim = normed @ normed^T, four reductions fused, never materialized.
// fp16 split: x = h + l, A2 = [H|L] (8192 x 512 fp16). A2·A2^T = HH^T + LL^T;
// dropped cross terms ~1e-5 -> negligible through the MLP+sigmoid.
#define NROWS 8192
#define DIM   256
#define K2    512
#define NTB   64                    // 8192/128 tiles per side
#define SIM_THR 0.85f

// d_ws layout: [0:16) header | [1024 : 1024+8MB) A2 fp16 | edges after
#define A2_OFF   1024
#define EDGE_OFF (1024 + NROWS * K2 * 2)

typedef _Float16 half8 __attribute__((ext_vector_type(8)));
typedef float f32x4 __attribute__((ext_vector_type(4)));

__device__ inline void load_lds16(const void* g, void* l) {
    __builtin_amdgcn_global_load_lds((const __attribute__((address_space(1))) void*)g,
                                     (__attribute__((address_space(3))) void*)l, 16, 0, 0);
}

__device__ inline void atomicMaxF(float* addr, float val) {
    if (val >= 0.f) atomicMax((int*)addr, __float_as_int(val));
    else            atomicMin((unsigned int*)addr, __float_as_uint(val));
}

// One wave per row: normalize (fp32), split to fp16 h/l, write A2 = [H|L].
// Block 0 thread 0 also initializes the reduction header.
__global__ __launch_bounds__(256) void prep_kernel(const float* __restrict__ x,
                                                   unsigned short* __restrict__ a2,
                                                   float* wsf) {
    if (blockIdx.x == 0 && threadIdx.x == 0) {
        wsf[0] = -INFINITY; wsf[1] = 0.f;
        ((unsigned int*)wsf)[2] = 0u; ((unsigned int*)wsf)[3] = 0u;
    }
    int row  = blockIdx.x * 4 + (threadIdx.x >> 6);
    int lane = threadIdx.x & 63;
    float4 v = ((const float4*)(x + (size_t)row * DIM))[lane];
    float ss = v.x * v.x + v.y * v.y + v.z * v.z + v.w * v.w;
    #pragma unroll
    for (int off = 32; off; off >>= 1) ss += __shfl_xor(ss, off);
    float norm = fmaxf(sqrtf(ss), 1e-12f);
    float f[4] = {v.x / norm, v.y / norm, v.z / norm, v.w / norm};
    unsigned short h[4], l[4];
    #pragma unroll
    for (int j = 0; j < 4; ++j) {
        _Float16 hh = (_Float16)f[j];
        _Float16 ll = (_Float16)(f[j] - (float)hh);
        h[j] = __builtin_bit_cast(unsigned short, hh);
        l[j] = __builtin_bit_cast(unsigned short, ll);
    }
    unsigned short* rp = a2 + (size_t)row * K2;
    *(ushort4*)(rp + lane * 4)       = make_ushort4(h[0], h[1], h[2], h[3]);
    *(ushort4*)(rp + DIM + lane * 4) = make_ushort4(l[0], l[1], l[2], l[3]);
}

// 128x128 tile per block (lower-tri tiles only), 4 waves at 2x2, 64x64 per wave,
// mfma_f32_16x16x32_f16, K=512 in 8 chunks of 64. XOR-swizzled LDS (rule #21:
// linear gload_lds dest + inverse-permuted global src + swizzled ds_read_b128).
__global__ __launch_bounds__(256) void sim_kernel(const unsigned short* __restrict__ a2,
                                                  float* wsf, int2* edges, int cap) {
    int idx = blockIdx.x;
    int bi = (int)((sqrtf(8.f * idx + 1.f) - 1.f) * 0.5f);
    while ((bi + 1) * (bi + 2) / 2 <= idx) ++bi;
    while (bi * (bi + 1) / 2 > idx) --bi;
    int bj = idx - bi * (bi + 1) / 2;          // bj <= bi
    int i0 = bi * 128, j0 = bj * 128;

    __shared__ __align__(16) char As[128 * 128];   // 16 KB, 128 B per row
    __shared__ __align__(16) char Bs[128 * 128];
    __shared__ float sred[12];

    int t = threadIdx.x, lane = t & 63, w = t >> 6;
    int wr = w >> 1, wc = w & 1;

    f32x4 acc[4][4] = {};

    // staging: wave w covers rows [w*32, w*32+32), 4 calls x 8 rows each.
    // lane i -> row +(i>>3), global col-bytes ((i&7)^(i>>3))*16 (inverse swizzle).
    int perm = ((lane & 7) ^ (lane >> 3)) * 16;
    const char* gA = (const char*)(a2 + (size_t)(i0 + w * 32 + (lane >> 3)) * K2) + perm;
    const char* gB = (const char*)(a2 + (size_t)(j0 + w * 32 + (lane >> 3)) * K2) + perm;
    char* lA = As + w * 32 * 128;
    char* lB = Bs + w * 32 * 128;

    int rbA = (wr * 64 + (lane & 15)) * 128;   // LDS byte row base, + m*16*128
    int rbB = (wc * 64 + (lane & 15)) * 128;
    int kx  = (lane & 7) << 4;                 // read-side XOR
    int kb0 = (lane >> 4) * 16;                // k-group byte offset

    for (int kc = 0; kc < 1024; kc += 128) {   // kc: byte offset within a row
        #pragma unroll
        for (int q = 0; q < 4; ++q) {
            load_lds16(gA + kc + q * 8192, lA + q * 1024);
            load_lds16(gB + kc + q * 8192, lB + q * 1024);
        }
        __syncthreads();

        #pragma unroll
        for (int ks = 0; ks < 2; ++ks) {
            int kb = ks * 64 + kb0;
            half8 af[4], bf[4];
            #pragma unroll
            for (int m = 0; m < 4; ++m) {
                af[m] = *(const half8*)(As + rbA + m * 2048 + (kb ^ kx));
                bf[m] = *(const half8*)(Bs + rbB + m * 2048 + (kb ^ kx));
            }
            #pragma unroll
            for (int m = 0; m < 4; ++m)
                #pragma unroll
                for (int n = 0; n < 4; ++n)
                    acc[m][n] = __builtin_amdgcn_mfma_f32_16x16x32_f16(af[m], bf[n], acc[m][n], 0, 0, 0);
        }
        __syncthreads();
    }

    // fused epilogue: C/D layout col=lane&15, row=(lane>>4)*4+reg (m89-verified)
    bool diagT = (bi == bj);
    float        wgt  = diagT ? 1.f : 2.f;
    unsigned int wgtu = diagT ? 1u : 2u;
    float lmax = -INFINITY, lsum = 0.f;
    unsigned int lcnt = 0;
    #pragma unroll
    for (int m = 0; m < 4; ++m) {
        #pragma unroll
        for (int n = 0; n < 4; ++n) {
            #pragma unroll
            for (int j = 0; j < 4; ++j) {
                float s = acc[m][n][j];
                int gi = i0 + wr * 64 + m * 16 + (lane >> 4) * 4 + j;
                int gj = j0 + wc * 64 + n * 16 + (lane & 15);
                if (gi != gj) {
                    lmax = fmaxf(lmax, s);
                    lsum += s;
                    if (s > SIM_THR) {
                        lcnt++;
                        unsigned int e = atomicAdd(&((unsigned int*)wsf)[3], 1u);
                        if (e < (unsigned int)cap) edges[e] = make_int2(gi, gj);
                    }
                }
            }
        }
    }
    #pragma unroll
    for (int off = 32; off; off >>= 1) {
        lmax = fmaxf(lmax, __shfl_xor(lmax, off));
        lsum += __shfl_xor(lsum, off);
        lcnt += __shfl_xor(lcnt, off);
    }
    if (lane == 0) { sred[w] = lmax; sred[4 + w] = lsum; ((unsigned int*)sred)[8 + w] = lcnt; }
    __syncthreads();
    if (t == 0) {
        float bm = fmaxf(fmaxf(sred[0], sred[1]), fmaxf(sred[2], sred[3]));
        float bs = sred[4] + sred[5] + sred[6] + sred[7];
        unsigned int bc = ((unsigned int*)sred)[8] + ((unsigned int*)sred)[9]
                        + ((unsigned int*)sred)[10] + ((unsigned int*)sred)[11];
        atomicMaxF(&wsf[0], bm);
        atomicAdd(&wsf[1], bs * wgt);
        if (bc) atomicAdd(&((unsigned int*)wsf)[2], bc * wgtu);
    }
}

// Single block: reference's exact 16-iter min-label + pointer-jump (LDS labels),
// early-exit when no edges (labels provably stay identity), then features + MLP.
__global__ __launch_bounds__(1024) void finalize_kernel(const float* wsf, const int2* edges, int cap,
                                                        const float* __restrict__ w1,
                                                        const float* __restrict__ b1,
                                                        const float* __restrict__ w2,
                                                        const float* __restrict__ b2,
                                                        float* __restrict__ out) {
    __shared__ int lab[NROWS];
    __shared__ int tmp[NROWS];
    __shared__ int wsum[16];
    int t = threadIdx.x;
    for (int i = t; i < NROWS; i += 1024) lab[i] = i;
    unsigned int ec = ((const unsigned int*)wsf)[3];
    if (ec > (unsigned int)cap) ec = (unsigned int)cap;
    __syncthreads();

    if (ec > 0) {
        for (int it = 0; it < 16; ++it) {   // ceil(log2(8192)) + 3 = 16, as reference
            for (int i = t; i < NROWS; i += 1024) tmp[i] = lab[i];
            __syncthreads();
            for (unsigned int e = t; e < ec; e += 1024) {
                int u = edges[e].x, v = edges[e].y;
                atomicMin(&tmp[u], lab[v]);
                atomicMin(&tmp[v], lab[u]);
            }
            __syncthreads();
            for (int i = t; i < NROWS; i += 1024) lab[i] = tmp[tmp[i]];
            __syncthreads();
        }
    }

    int lc = 0;
    for (int i = t; i < NROWS; i += 1024) lc += (lab[i] == i);
    #pragma unroll
    for (int off = 32; off; off >>= 1) lc += __shfl_xor(lc, off);
    if ((t & 63) == 0) wsum[t >> 6] = lc;
    __syncthreads();

    if (t == 0) {
        int roots = 0;
        #pragma unroll
        for (int q = 0; q < 16; ++q) roots += wsum[q];
        const float n_pairs = 67100672.0f;             // 8192*8191
        float feats[4];
        feats[0] = wsf[0];
        feats[1] = wsf[1] / n_pairs;
        feats[2] = (float)((const unsigned int*)wsf)[2] / n_pairs;
        feats[3] = (float)roots / (float)NROWS;
        float acc2 = b2[0];
        for (int j = 0; j < 16; ++j) {
            float hj = b1[j];
            #pragma unroll
            for (int i = 0; i < 4; ++i) hj = fmaf(feats[i], w1[i * 16 + j], hj);
            float g = 0.5f * hj * (1.0f + erff(hj * 0.70710678118f));
            acc2 = fmaf(g, w2[j], acc2);
        }
        out[0] = 1.0f / (1.0f + expf(-acc2));
    }
}

extern "C" void kernel_launch(void* const* d_in, const int* in_sizes, int n_in,
                              void* d_out, int out_size, void* d_ws, size_t ws_size,
                              hipStream_t stream) {
    const float* cls = (const float*)d_in[0];
    const float* w1  = (const float*)d_in[1];
    const float* b1  = (const float*)d_in[2];
    const float* w2  = (const float*)d_in[3];
    const float* b2  = (const float*)d_in[4];
    float* out = (float*)d_out;

    float* wsf = (float*)d_ws;
    unsigned short* a2 = (unsigned short*)((char*)d_ws + A2_OFF);
    int2* edges = (int2*)((char*)d_ws + EDGE_OFF);
    long long avail = (long long)ws_size - (long long)EDGE_OFF;
    int cap = (int)(avail > 0 ? (avail / 8 > 4194304 ? 4194304 : avail / 8) : 0);

    prep_kernel<<<NROWS / 4, 256, 0, stream>>>(cls, a2, wsf);
    sim_kernel<<<NTB * (NTB + 1) / 2, 256, 0, stream>>>(a2, wsf, edges, cap);
    finalize_kernel<<<1, 1024, 0, stream>>>(wsf, edges, cap, w1, b1, w2, b2, out);
}

// Round 3
// 138.001 us; speedup vs baseline: 2.9995x; 1.0955x over previous
//
#include <hip/hip_runtime.h>
#include <math.h>

// N=8192, D=256. sim = normed @ normed^T; four reductions fused, sim never materialized.
// fp16 split: x = h + l, A2 = [H|L] (8192 x 512 fp16). A2·A2^T = HH^T + LL^T.
#define NROWS 8192
#define DIM   256
#define K2    512                  // fp16 elems per row (1024 B)
#define NTB   32                   // 8192/256 tiles per side
#define SIM_THR 0.85f

#define A2_OFF   1024
#define EDGE_OFF (1024 + NROWS * K2 * 2)

typedef _Float16 half8 __attribute__((ext_vector_type(8)));
typedef float f32x4 __attribute__((ext_vector_type(4)));

__device__ inline void load_lds16(const void* g, void* l) {
    __builtin_amdgcn_global_load_lds((const __attribute__((address_space(1))) void*)g,
                                     (__attribute__((address_space(3))) void*)l, 16, 0, 0);
}

__device__ inline void atomicMaxF(float* addr, float val) {
    if (val >= 0.f) atomicMax((int*)addr, __float_as_int(val));
    else            atomicMin((unsigned int*)addr, __float_as_uint(val));
}

// One wave per row: normalize (fp32), split to fp16 h/l, write A2 = [H|L].
__global__ __launch_bounds__(256) void prep_kernel(const float* __restrict__ x,
                                                   unsigned short* __restrict__ a2,
                                                   float* wsf) {
    if (blockIdx.x == 0 && threadIdx.x == 0) {
        wsf[0] = -INFINITY; wsf[1] = 0.f;
        ((unsigned int*)wsf)[2] = 0u; ((unsigned int*)wsf)[3] = 0u;
    }
    int row  = blockIdx.x * 4 + (threadIdx.x >> 6);
    int lane = threadIdx.x & 63;
    float4 v = ((const float4*)(x + (size_t)row * DIM))[lane];
    float ss = v.x * v.x + v.y * v.y + v.z * v.z + v.w * v.w;
    #pragma unroll
    for (int off = 32; off; off >>= 1) ss += __shfl_xor(ss, off);
    float norm = fmaxf(sqrtf(ss), 1e-12f);
    float f[4] = {v.x / norm, v.y / norm, v.z / norm, v.w / norm};
    unsigned short h[4], l[4];
    #pragma unroll
    for (int j = 0; j < 4; ++j) {
        _Float16 hh = (_Float16)f[j];
        _Float16 ll = (_Float16)(f[j] - (float)hh);
        h[j] = __builtin_bit_cast(unsigned short, hh);
        l[j] = __builtin_bit_cast(unsigned short, ll);
    }
    unsigned short* rp = a2 + (size_t)row * K2;
    *(ushort4*)(rp + lane * 4)       = make_ushort4(h[0], h[1], h[2], h[3]);
    *(ushort4*)(rp + DIM + lane * 4) = make_ushort4(l[0], l[1], l[2], l[3]);
}

// 256x256 tile per block (lower-tri tiles), 512 threads = 8 waves (2x4), wave-tile
// 128x64, mfma_f32_16x16x32_f16. Double-buffered LDS (2 x 64 KB), prefetch-ahead
// 2-phase: STAGE(next) issued BEFORE compute(cur); single barrier per iter whose
// implicit vmcnt(0) drain lands after ~2400 cy of MFMA. Both-sides XOR swizzle
// (verified conflict-free in round 2).
__global__ __launch_bounds__(512, 2) void sim_kernel(const unsigned short* __restrict__ a2,
                                                     float* wsf, int2* edges, int cap) {
    int idx = blockIdx.x;
    int bi = (int)((sqrtf(8.f * idx + 1.f) - 1.f) * 0.5f);
    while ((bi + 1) * (bi + 2) / 2 <= idx) ++bi;
    while (bi * (bi + 1) / 2 > idx) --bi;
    int bj = idx - bi * (bi + 1) / 2;          // bj <= bi
    int i0 = bi * 256, j0 = bj * 256;

    __shared__ __align__(16) char As[2][256 * 128];   // 32 KB each
    __shared__ __align__(16) char Bs[2][256 * 128];
    __shared__ float sred[24];

    int t = threadIdx.x, lane = t & 63, w = t >> 6;   // w: 0..7
    int wr = w >> 2, wc = w & 3;                       // 2x4 wave grid

    f32x4 acc[8][4] = {};

    // staging: wave w stages rows [w*32, w*32+32) of A and B; 4 calls each,
    // lane i -> row +(i>>3), global col-bytes ((i&7)^(i>>3))*16 (inverse swizzle),
    // LDS dest linear (gload_lds writes base + lane*16).
    int perm = ((lane & 7) ^ (lane >> 3)) * 16;
    const char* gA = (const char*)a2 + (size_t)(i0 + w * 32 + (lane >> 3)) * 1024 + perm;
    const char* gB = (const char*)a2 + (size_t)(j0 + w * 32 + (lane >> 3)) * 1024 + perm;
    int ldsW = w * 32 * 128;                           // wave's 32-row slab

    int rbA = (wr * 128 + (lane & 15)) * 128;          // frag row base (bytes)
    int rbB = (wc * 64  + (lane & 15)) * 128;
    int kx  = (lane & 7) << 4;                         // read-side XOR
    int kb0 = (lane >> 4) << 4;                        // k-group byte offset

    // prologue: stage chunk 0 into buffer 0
    #pragma unroll
    for (int q = 0; q < 4; ++q) {
        load_lds16(gA + q * 8192, As[0] + ldsW + q * 1024);
        load_lds16(gB + q * 8192, Bs[0] + ldsW + q * 1024);
    }
    __syncthreads();

    int cur = 0;
    for (int it = 0; it < 8; ++it) {                   // K = 512 elem = 8 x 128 B
        if (it < 7) {
            int kc = (it + 1) * 128;
            #pragma unroll
            for (int q = 0; q < 4; ++q) {
                load_lds16(gA + kc + q * 8192, As[cur ^ 1] + ldsW + q * 1024);
                load_lds16(gB + kc + q * 8192, Bs[cur ^ 1] + ldsW + q * 1024);
            }
        }
        const char* A = As[cur];
        const char* B = Bs[cur];
        #pragma unroll
        for (int ks = 0; ks < 2; ++ks) {
            int kb = (ks * 64 + kb0) ^ kx;
            half8 af[8], bf[4];
            #pragma unroll
            for (int m = 0; m < 8; ++m) af[m] = *(const half8*)(A + rbA + m * 2048 + kb);
            #pragma unroll
            for (int n = 0; n < 4; ++n) bf[n] = *(const half8*)(B + rbB + n * 2048 + kb);
            #pragma unroll
            for (int m = 0; m < 8; ++m)
                #pragma unroll
                for (int n = 0; n < 4; ++n)
                    acc[m][n] = __builtin_amdgcn_mfma_f32_16x16x32_f16(af[m], bf[n], acc[m][n], 0, 0, 0);
        }
        __syncthreads();   // implicit vmcnt(0): next buffer staged; cur safe to overwrite
        cur ^= 1;
    }

    // fused epilogue: C/D layout col=lane&15, row=(lane>>4)*4+reg (m89-verified)
    bool diagT = (bi == bj);
    float        wgt  = diagT ? 1.f : 2.f;
    unsigned int wgtu = diagT ? 1u : 2u;
    float lmax = -INFINITY, lsum = 0.f;
    unsigned int lcnt = 0;
    #pragma unroll
    for (int m = 0; m < 8; ++m) {
        #pragma unroll
        for (int n = 0; n < 4; ++n) {
            #pragma unroll
            for (int j = 0; j < 4; ++j) {
                float s = acc[m][n][j];
                int gi = i0 + wr * 128 + m * 16 + (lane >> 4) * 4 + j;
                int gj = j0 + wc * 64  + n * 16 + (lane & 15);
                if (gi != gj) {
                    lmax = fmaxf(lmax, s);
                    lsum += s;
                    if (s > SIM_THR) {
                        lcnt++;
                        unsigned int e = atomicAdd(&((unsigned int*)wsf)[3], 1u);
                        if (e < (unsigned int)cap) edges[e] = make_int2(gi, gj);
                    }
                }
            }
        }
    }
    #pragma unroll
    for (int off = 32; off; off >>= 1) {
        lmax = fmaxf(lmax, __shfl_xor(lmax, off));
        lsum += __shfl_xor(lsum, off);
        lcnt += __shfl_xor(lcnt, off);
    }
    if (lane == 0) { sred[w] = lmax; sred[8 + w] = lsum; ((unsigned int*)sred)[16 + w] = lcnt; }
    __syncthreads();
    if (t == 0) {
        float bm = -INFINITY, bs = 0.f;
        unsigned int bc = 0;
        #pragma unroll
        for (int q = 0; q < 8; ++q) {
            bm = fmaxf(bm, sred[q]);
            bs += sred[8 + q];
            bc += ((unsigned int*)sred)[16 + q];
        }
        atomicMaxF(&wsf[0], bm);
        atomicAdd(&wsf[1], bs * wgt);
        if (bc) atomicAdd(&((unsigned int*)wsf)[2], bc * wgtu);
    }
}

// Single block: reference's exact 16-iter min-label + pointer-jump (LDS labels),
// early-exit when no edges (labels provably stay identity), then features + MLP.
__global__ __launch_bounds__(1024) void finalize_kernel(const float* wsf, const int2* edges, int cap,
                                                        const float* __restrict__ w1,
                                                        const float* __restrict__ b1,
                                                        const float* __restrict__ w2,
                                                        const float* __restrict__ b2,
                                                        float* __restrict__ out) {
    __shared__ int lab[NROWS];
    __shared__ int tmp[NROWS];
    __shared__ int wsum[16];
    int t = threadIdx.x;
    for (int i = t; i < NROWS; i += 1024) lab[i] = i;
    unsigned int ec = ((const unsigned int*)wsf)[3];
    if (ec > (unsigned int)cap) ec = (unsigned int)cap;
    __syncthreads();

    if (ec > 0) {
        for (int it = 0; it < 16; ++it) {   // ceil(log2(8192)) + 3 = 16, as reference
            for (int i = t; i < NROWS; i += 1024) tmp[i] = lab[i];
            __syncthreads();
            for (unsigned int e = t; e < ec; e += 1024) {
                int u = edges[e].x, v = edges[e].y;
                atomicMin(&tmp[u], lab[v]);
                atomicMin(&tmp[v], lab[u]);
            }
            __syncthreads();
            for (int i = t; i < NROWS; i += 1024) lab[i] = tmp[tmp[i]];
            __syncthreads();
        }
    }

    int lc = 0;
    for (int i = t; i < NROWS; i += 1024) lc += (lab[i] == i);
    #pragma unroll
    for (int off = 32; off; off >>= 1) lc += __shfl_xor(lc, off);
    if ((t & 63) == 0) wsum[t >> 6] = lc;
    __syncthreads();

    if (t == 0) {
        int roots = 0;
        #pragma unroll
        for (int q = 0; q < 16; ++q) roots += wsum[q];
        const float n_pairs = 67100672.0f;             // 8192*8191
        float feats[4];
        feats[0] = wsf[0];
        feats[1] = wsf[1] / n_pairs;
        feats[2] = (float)((const unsigned int*)wsf)[2] / n_pairs;
        feats[3] = (float)roots / (float)NROWS;
        float acc2 = b2[0];
        for (int j = 0; j < 16; ++j) {
            float hj = b1[j];
            #pragma unroll
            for (int i = 0; i < 4; ++i) hj = fmaf(feats[i], w1[i * 16 + j], hj);
            float g = 0.5f * hj * (1.0f + erff(hj * 0.70710678118f));
            acc2 = fmaf(g, w2[j], acc2);
        }
        out[0] = 1.0f / (1.0f + expf(-acc2));
    }
}

extern "C" void kernel_launch(void* const* d_in, const int* in_sizes, int n_in,
                              void* d_out, int out_size, void* d_ws, size_t ws_size,
                              hipStream_t stream) {
    const float* cls = (const float*)d_in[0];
    const float* w1  = (const float*)d_in[1];
    const float* b1  = (const float*)d_in[2];
    const float* w2  = (const float*)d_in[3];
    const float* b2  = (const float*)d_in[4];
    float* out = (float*)d_out;

    float* wsf = (float*)d_ws;
    unsigned short* a2 = (unsigned short*)((char*)d_ws + A2_OFF);
    int2* edges = (int2*)((char*)d_ws + EDGE_OFF);
    long long avail = (long long)ws_size - (long long)EDGE_OFF;
    int cap = (int)(avail > 0 ? (avail / 8 > 4194304 ? 4194304 : avail / 8) : 0);

    prep_kernel<<<NROWS / 4, 256, 0, stream>>>(cls, a2, wsf);
    sim_kernel<<<NTB * (NTB + 1) / 2, 512, 0, stream>>>(a2, wsf, edges, cap);
    finalize_kernel<<<1, 1024, 0, stream>>>(wsf, edges, cap, w1, b1, w2, b2, out);
}